// Round 11
// baseline (676.064 us; speedup 1.0000x reference)
//
#include <hip/hip_runtime.h>
#include <math.h>

#define NT 30
#define TT 60
#define S  90
#define NN 48
#define SS (S*S)            // 8100
#define RSZ (NT*SS)         // 243000
#define PB 72               // bf16 LDS pitch (144B; 36-dword row stride -> conflict-light)
#define NACH 6              // nonterminals per item
#define NCHUNK 5            // items per cell
#define NITEMS (1128 * NCHUNK)

typedef __attribute__((ext_vector_type(8))) short bf16x8;
typedef __attribute__((ext_vector_type(4))) float f32x4;

__device__ __forceinline__ unsigned ordKey(float f) {
    unsigned u = __float_as_uint(f);
    return (u & 0x80000000u) ? ~u : (u | 0x80000000u);
}
__device__ __forceinline__ float decKey(unsigned k) {
    unsigned u = (k & 0x80000000u) ? (k ^ 0x80000000u) : ~k;
    return __uint_as_float(u);
}
__device__ __forceinline__ unsigned short f2bf(float f) {
    unsigned u = __float_as_uint(f);
    return (unsigned short)((u + 0x7fffu + ((u >> 16) & 1u)) >> 16);
}
__device__ __forceinline__ float bf2f(unsigned short h) {
    return __uint_as_float(((unsigned)h) << 16);
}

// 128 blocks x 256: rule-max partials; blocks 0..47 also init diag svec/scal/mkey/done.
__global__ void k_rmax1init(const float* __restrict__ rule, const float* __restrict__ unary,
                            float* __restrict__ rpart, unsigned short* __restrict__ svec,
                            float* __restrict__ scal, unsigned* __restrict__ mkey,
                            unsigned* __restrict__ done) {
    __shared__ float red[256];
    __shared__ float mxs;
    float v = -INFINITY;
    for (int i = blockIdx.x * 256 + threadIdx.x; i < RSZ; i += 256 * 128)
        v = fmaxf(v, rule[i]);
    red[threadIdx.x] = v;
    __syncthreads();
    for (int s = 128; s > 0; s >>= 1) {
        if (threadIdx.x < s) red[threadIdx.x] = fmaxf(red[threadIdx.x], red[threadIdx.x + s]);
        __syncthreads();
    }
    if (threadIdx.x == 0) rpart[blockIdx.x] = red[0];

    const int i = blockIdx.x;
    if (i < NN) {
        const int t = threadIdx.x;
        if (t < 64) {
            float u = (t < TT) ? unary[i * TT + t] : -INFINITY;
            for (int o = 32; o > 0; o >>= 1) u = fmaxf(u, __shfl_down(u, o));
            if (t == 0) mxs = u;
        }
        __syncthreads();
        const float mx = mxs;
        if (t < 96)
            svec[(i * NN + i) * 96 + t] =
                (t >= NT && t < S) ? f2bf(__expf(unary[i * TT + (t - NT)] - mx)) : (unsigned short)0;
        if (t == 0) scal[i * NN + i] = mx;
        if (t < NN) {
            mkey[i * NN + t] = (t == i) ? ordKey(mx) : 0u;
            done[i * NN + t] = (t == i) ? (unsigned)NCHUNK : 0u;
        }
    }
}

// grid (30,36) x 64: finish rule-max reduce; write rmax + bf16 tile-major erule.
__global__ void k_eruleB(const float* __restrict__ rule, const float* __restrict__ rpart,
                         float* __restrict__ rmax, unsigned short* __restrict__ eruleB) {
    const int a    = blockIdx.x;
    const int tIdx = blockIdx.y;
    const int lane = threadIdx.x;   // 64
    float v = fmaxf(rpart[lane], rpart[lane + 64]);
    for (int o = 32; o > 0; o >>= 1) v = fmaxf(v, __shfl_down(v, o));
    const float Rm = __shfl(v, 0);
    if (a == 0 && tIdx == 0 && lane == 0) rmax[0] = Rm;

    const int bt = tIdx / 6, ct = tIdx - bt * 6;
    ushort4 vv;
    unsigned short* pv = (unsigned short*)&vv;
#pragma unroll
    for (int reg = 0; reg < 4; ++reg) {
        int b = bt * 16 + (lane >> 4) * 4 + reg;
        int c = ct * 16 + (lane & 15);
        float val = (b < S && c < S) ? __expf(rule[a * SS + b * S + c] - Rm) : 0.f;
        pv[reg] = f2bf(val);
    }
    *(ushort4*)(eruleB + ((a * 36 + tIdx) * 64 + lane) * 4) = vv;
}

// Persistent cooperative dataflow kernel. No grid.sync; per-cell done counters.
__global__ __launch_bounds__(384, 1) void k_all(const unsigned short* __restrict__ eruleB,
                                                const float* __restrict__ rmax,
                                                const float* __restrict__ root,
                                                unsigned short* __restrict__ svec,
                                                float* __restrict__ scal,
                                                unsigned* __restrict__ mkey,
                                                unsigned* __restrict__ done,
                                                float* __restrict__ out) {
    const int tid  = threadIdx.x;
    const int lane = tid & 63;
    const int w    = tid >> 6;

    __shared__ unsigned short elT[96 * PB];
    __shared__ unsigned short erT[96 * PB];
    __shared__ float fL[47], fR[47];
    __shared__ float part[NACH][6];
    __shared__ float Msh;

    const float Rm = rmax[0];

    for (int it = blockIdx.x; it < NITEMS; it += (int)gridDim.x) {
        // ---- decode item -> (l, s0, chunk) ----
        int rem = it, l = 1;
        while (rem >= (NN - l) * NCHUNK) { rem -= (NN - l) * NCHUNK; ++l; }
        const int s0    = rem / NCHUNK;
        const int chunk = rem - s0 * NCHUNK;
        const int j     = s0 + l;
        const int cell  = s0 * NN + j;
        const int a0    = chunk * NACH;

        // ---- A: wave0 polls deps (stale-proof RMW reads); waves 1-5 zero LDS ----
        if (w == 0) {
            int guard = 0;
            for (;;) {
                bool ok = true;
                for (int r = lane; r < 2 * l; r += 64) {
                    int ci = (r < l) ? (s0 * NN + s0 + r) : ((s0 + (r - l) + 1) * NN + j);
                    ok &= (atomicAdd(&done[ci], 0u) >= (unsigned)NCHUNK);
                }
                if (__all(ok)) break;
                if (++guard > (1 << 17)) break;   // safety valve: fail fast, never hang
                __builtin_amdgcn_s_sleep(2);
            }
        } else {
            uint4 z = {0u, 0u, 0u, 0u};
            uint4* z1 = (uint4*)elT;
            uint4* z2 = (uint4*)erT;
            for (int i = tid - 64; i < 96 * PB / 8; i += 320) { z1[i] = z; z2[i] = z; }
        }
        __syncthreads();
        __builtin_amdgcn_fence(__ATOMIC_ACQUIRE, "agent");

        // ---- B: wave0 computes per-split factors ----
        if (w == 0) {
            float msum = -INFINITY, sl = 0.f, sr = 0.f, mrv = 0.f;
            if (lane < l) {
                int cl = s0 * NN + s0 + lane;
                int cr = (s0 + lane + 1) * NN + j;
                float mlv = decKey(mkey[cl]);
                mrv = decKey(mkey[cr]);
                sl = scal[cl]; sr = scal[cr];
                msum = mlv + mrv;
            }
            float v = msum;
            for (int o = 32; o > 0; o >>= 1) v = fmaxf(v, __shfl_down(v, o));
            float M = __shfl(v, 0);
            if (lane == 0) Msh = M;
            if (lane < l) {
                fL[lane] = __expf(sl + mrv - M);
                fR[lane] = __expf(sr - mrv);
            }
        }
        __syncthreads();

        // ---- C: stage bf16 * per-row factor, transposed ----
        const unsigned short* lb = svec + (s0 * NN + s0) * 96;
        for (int i = tid; i < l * S; i += 384) {
            int r = i / S, x = i - r * S;
            elT[x * PB + r] = f2bf(bf2f(lb[r * 96 + x]) * fL[r]);
            erT[x * PB + r] = f2bf(bf2f(svec[((s0 + r + 1) * NN + j) * 96 + x]) * fR[r]);
        }
        __syncthreads();

        // ---- D: G via MFMA, 6 waves x 6 col-tiles ----
        const int K = (l > 32) ? 64 : 32;
        f32x4 acc[6];
        {
            f32x4 zz = {0.f, 0.f, 0.f, 0.f};
#pragma unroll
            for (int tc = 0; tc < 6; ++tc) acc[tc] = zz;
        }
        const int arow = w * 16 + (lane & 15);
        const int koff = (lane >> 4) * 8;
        for (int ks = 0; ks < (K >> 5); ++ks) {
            bf16x8 af = *(const bf16x8*)(elT + arow * PB + ks * 32 + koff);
#pragma unroll
            for (int tc = 0; tc < 6; ++tc) {
                bf16x8 bfr = *(const bf16x8*)(erT + (tc * 16 + (lane & 15)) * PB + ks * 32 + koff);
                acc[tc] = __builtin_amdgcn_mfma_f32_16x16x32_bf16(af, bfr, acc[tc], 0, 0, 0);
            }
        }

        // ---- E: contraction, 6 a's, coalesced bf16 tile loads ----
        float pv[NACH];
#pragma unroll
        for (int ai = 0; ai < NACH; ++ai) pv[ai] = 0.f;
#pragma unroll
        for (int ai = 0; ai < NACH; ++ai) {
            const unsigned short* rp = eruleB + ((a0 + ai) * 36 + w * 6) * 256 + lane * 4;
#pragma unroll
            for (int tc = 0; tc < 6; ++tc) {
                uint2 rv = *(const uint2*)(rp + tc * 256);
                float r0 = __uint_as_float((rv.x & 0xffffu) << 16);
                float r1 = __uint_as_float(rv.x & 0xffff0000u);
                float r2 = __uint_as_float((rv.y & 0xffffu) << 16);
                float r3 = __uint_as_float(rv.y & 0xffff0000u);
                pv[ai] += r0 * acc[tc][0] + r1 * acc[tc][1]
                        + r2 * acc[tc][2] + r3 * acc[tc][3];
            }
        }
#pragma unroll
        for (int ai = 0; ai < NACH; ++ai) {
            float p = pv[ai];
            for (int o = 32; o > 0; o >>= 1) p += __shfl_down(p, o);
            if (lane == 0) part[ai][w] = p;
        }
        __syncthreads();

        // ---- F: epilogue writes ----
        if (chunk == 0) {
            if (tid >= NT && tid < 96) svec[cell * 96 + tid] = 0;
            if (tid == 0) scal[cell] = Msh + Rm;
        }
        if (tid < NACH) {
            float sum = part[tid][0] + part[tid][1] + part[tid][2]
                      + part[tid][3] + part[tid][4] + part[tid][5];
            float alpha = Msh + Rm + logf(sum);
            svec[cell * 96 + a0 + tid] = f2bf(sum);
            atomicMax(&mkey[cell], ordKey(alpha));
        }
        __syncthreads();   // all epilogue writes drained (per-wave vmcnt before barrier)

        // ---- G: release + signal; last finisher of top cell emits the output ----
        if (tid == 0) {
            __builtin_amdgcn_fence(__ATOMIC_RELEASE, "agent");
            unsigned old = __hip_atomic_fetch_add(&done[cell], 1u, __ATOMIC_ACQ_REL,
                                                  __HIP_MEMORY_SCOPE_AGENT);
            if (old == (unsigned)(NCHUNK - 1) && cell == NN - 1) {
                float sc = scal[cell];
                float accf = 0.f;
#pragma unroll
                for (int a = 0; a < NT; ++a)
                    accf += bf2f(svec[cell * 96 + a]) * __expf(root[a]);
                out[0] = sc + logf(accf);
            }
        }
    }
}

extern "C" void kernel_launch(void* const* d_in, const int* in_sizes, int n_in,
                              void* d_out, int out_size, void* d_ws, size_t ws_size,
                              hipStream_t stream) {
    const float* unary = (const float*)d_in[0];  // (48,60)
    const float* rule  = (const float*)d_in[1];  // (30,90,90)
    const float* root  = (const float*)d_in[2];  // (30,)
    float* out = (float*)d_out;

    float*          ws     = (float*)d_ws;
    unsigned short* eruleB = (unsigned short*)ws;           // 276480 ushorts
    unsigned short* svec   = eruleB + 30 * 36 * 256;        // 221184 ushorts
    float*          scal   = (float*)(svec + NN * NN * 96); // 2304 floats
    float*          rpart  = scal + NN * NN;                // 128
    float*          rmax   = rpart + 128;                   // 1 (+3 pad)
    unsigned*       mkey   = (unsigned*)(rmax + 4);         // 2304
    unsigned*       done   = mkey + NN * NN;                // 2304

    k_rmax1init<<<128, 256, 0, stream>>>(rule, unary, rpart, svec, scal, mkey, done);
    k_eruleB<<<dim3(30, 36), 64, 0, stream>>>(rule, rpart, rmax, eruleB);

    int nb = 0;
    hipOccupancyMaxActiveBlocksPerMultiprocessor(&nb, k_all, 384, 0);
    if (nb < 1) nb = 1;
    int grid = nb * 256;
    if (grid > NITEMS) grid = NITEMS;

    void* args[8] = { (void*)&eruleB, (void*)&rmax, (void*)&root, (void*)&svec,
                      (void*)&scal, (void*)&mkey, (void*)&done, (void*)&out };
    hipLaunchCooperativeKernel((const void*)k_all, dim3(grid), dim3(384),
                               args, 0, stream);
}

// Round 12
// 322.041 us; speedup vs baseline: 2.0993x; 2.0993x over previous
//
#include <hip/hip_runtime.h>
#include <math.h>

#define NT 30
#define TT 60
#define S  90
#define NN 48
#define SS (S*S)            // 8100
#define PB 72               // bf16 LDS pitch (144B)

typedef __attribute__((ext_vector_type(8))) short bf16x8;
typedef __attribute__((ext_vector_type(4))) float f32x4;

__device__ __forceinline__ unsigned ordKey(float f) {
    unsigned u = __float_as_uint(f);
    return (u & 0x80000000u) ? ~u : (u | 0x80000000u);
}
__device__ __forceinline__ float decKey(unsigned k) {
    unsigned u = (k & 0x80000000u) ? (k ^ 0x80000000u) : ~k;
    return __uint_as_float(u);
}
__device__ __forceinline__ unsigned short f2bf(float f) {
    unsigned u = __float_as_uint(f);
    return (unsigned short)((u + 0x7fffu + ((u >> 16) & 1u)) >> 16);
}
__device__ __forceinline__ float bf2f(unsigned short h) {
    return __uint_as_float(((unsigned)h) << 16);
}

// One prep kernel: blocks 0..1079 write bf16 tile-major erule (no max-shift);
// blocks 1080..1127 init diag svec/scal/mkey.
__global__ void k_prep(const float* __restrict__ rule, const float* __restrict__ unary,
                       unsigned short* __restrict__ eruleB, unsigned short* __restrict__ svec,
                       float* __restrict__ scal, unsigned* __restrict__ mkey) {
    const int b    = blockIdx.x;
    const int lane = threadIdx.x;   // 64
    if (b < 1080) {
        const int a = b / 36, tIdx = b - a * 36;
        const int bt = tIdx / 6, ct = tIdx - bt * 6;
        ushort4 vv;
        unsigned short* pv = (unsigned short*)&vv;
#pragma unroll
        for (int reg = 0; reg < 4; ++reg) {
            int bb = bt * 16 + (lane >> 4) * 4 + reg;
            int cc = ct * 16 + (lane & 15);
            float val = (bb < S && cc < S) ? __expf(rule[a * SS + bb * S + cc]) : 0.f;
            pv[reg] = f2bf(val);
        }
        *(ushort4*)(eruleB + ((a * 36 + tIdx) * 64 + lane) * 4) = vv;
    } else {
        const int i = b - 1080;
        float u = (lane < TT) ? unary[i * TT + lane] : -INFINITY;
        float m = u;
        for (int o = 32; o > 0; o >>= 1) m = fmaxf(m, __shfl_down(m, o));
        m = __shfl(m, 0);
        for (int t = lane; t < 96; t += 64)
            svec[(i * NN + i) * 96 + t] =
                (t >= NT && t < S) ? f2bf(__expf(unary[i * TT + (t - NT)] - m)) : (unsigned short)0;
        if (lane == 0) scal[i * NN + i] = m;
        if (lane < NN) mkey[i * NN + lane] = (lane == i) ? ordKey(m) : 0u;
    }
}

// grid (NN-l, 30): one block per (span, nonterminal).
__global__ __launch_bounds__(384, 1) void k_level(int l,
                                                  const unsigned short* __restrict__ eruleB,
                                                  unsigned short* __restrict__ svec,
                                                  float* __restrict__ scal,
                                                  unsigned* __restrict__ mkey) {
    const int s0   = blockIdx.x;
    const int a    = blockIdx.y;
    const int j    = s0 + l;
    const int cell = s0 * NN + j;
    const int tid  = threadIdx.x;
    const int lane = tid & 63;
    const int w    = tid >> 6;

    __shared__ unsigned short elT[96 * PB];
    __shared__ unsigned short erT[96 * PB];
    __shared__ float fL[48], fR[48];
    __shared__ float part[6];
    __shared__ float Msh;

    // ---- prefetch erule tiles for this (a, wave) into registers (independent) ----
    uint2 rv[6];
    {
        const unsigned short* rp = eruleB + (a * 36 + w * 6) * 256 + lane * 4;
#pragma unroll
        for (int tc = 0; tc < 6; ++tc) rv[tc] = *(const uint2*)(rp + tc * 256);
    }

    // ---- wave 0: per-split factors from scal/mkey tables ----
    if (w == 0) {
        float msum = -INFINITY, sl = 0.f, sr = 0.f, mrv = 0.f;
        if (lane < l) {
            int cl = s0 * NN + s0 + lane;
            int cr = (s0 + lane + 1) * NN + j;
            float mlv = decKey(mkey[cl]);
            mrv = decKey(mkey[cr]);
            sl = scal[cl]; sr = scal[cr];
            msum = mlv + mrv;
        }
        float v = msum;
        for (int o = 32; o > 0; o >>= 1) v = fmaxf(v, __shfl_down(v, o));
        float M = __shfl(v, 0);
        if (lane == 0) Msh = M;
        if (lane < l) {
            fL[lane] = __expf(sl + mrv - M);
            fR[lane] = __expf(sr - mrv);
        }
    }
    __syncthreads();

    // ---- fused zero+stage: one predicated pass over [96 x K] x 2 ----
    const int K = (l > 32) ? 64 : 32;
    const unsigned short* lb = svec + (s0 * NN + s0) * 96;   // left cells contiguous
    for (int i = tid; i < 96 * K; i += 384) {
        int r = i / 96, x = i - r * 96;
        float vl = 0.f, vr = 0.f;
        if (r < l) {
            vl = bf2f(lb[r * 96 + x]) * fL[r];
            vr = bf2f(svec[((s0 + r + 1) * NN + j) * 96 + x]) * fR[r];
        }
        elT[x * PB + r] = f2bf(vl);
        erT[x * PB + r] = f2bf(vr);
    }
    __syncthreads();

    // ---- G via MFMA: 6 waves x 6 col-tiles ----
    f32x4 acc[6];
    {
        f32x4 zz = {0.f, 0.f, 0.f, 0.f};
#pragma unroll
        for (int tc = 0; tc < 6; ++tc) acc[tc] = zz;
    }
    const int arow = w * 16 + (lane & 15);
    const int koff = (lane >> 4) * 8;
    for (int ks = 0; ks < (K >> 5); ++ks) {
        bf16x8 af = *(const bf16x8*)(elT + arow * PB + ks * 32 + koff);
#pragma unroll
        for (int tc = 0; tc < 6; ++tc) {
            bf16x8 bfr = *(const bf16x8*)(erT + (tc * 16 + (lane & 15)) * PB + ks * 32 + koff);
            acc[tc] = __builtin_amdgcn_mfma_f32_16x16x32_bf16(af, bfr, acc[tc], 0, 0, 0);
        }
    }

    // ---- contraction from prefetched registers ----
    float p = 0.f;
#pragma unroll
    for (int tc = 0; tc < 6; ++tc) {
        float r0 = __uint_as_float((rv[tc].x & 0xffffu) << 16);
        float r1 = __uint_as_float(rv[tc].x & 0xffff0000u);
        float r2 = __uint_as_float((rv[tc].y & 0xffffu) << 16);
        float r3 = __uint_as_float(rv[tc].y & 0xffff0000u);
        p += r0 * acc[tc][0] + r1 * acc[tc][1]
           + r2 * acc[tc][2] + r3 * acc[tc][3];
    }
    for (int o = 32; o > 0; o >>= 1) p += __shfl_down(p, o);
    if (lane == 0) part[w] = p;
    __syncthreads();

    // ---- finalize ----
    if (a == 0 && tid >= NT && tid < 96) svec[cell * 96 + tid] = 0;
    if (tid == 0) {
        float sum = part[0] + part[1] + part[2] + part[3] + part[4] + part[5];
        float alpha = Msh + logf(sum);
        svec[cell * 96 + a] = f2bf(sum);
        if (a == 0) scal[cell] = Msh;
        atomicMax(&mkey[cell], ordKey(alpha));
    }
}

__global__ void k_final(const float* __restrict__ root, const unsigned short* __restrict__ svec,
                        const float* __restrict__ scal, float* __restrict__ out) {
    const int t = threadIdx.x;  // 64
    const int cell = NN - 1;    // (0, 47)
    float v = (t < NT) ? scal[cell] + logf(bf2f(svec[cell * 96 + t])) + root[t] : -INFINITY;
    float m = v;
    for (int o = 32; o > 0; o >>= 1) m = fmaxf(m, __shfl_down(m, o));
    m = __shfl(m, 0);
    float e = (t < NT) ? __expf(v - m) : 0.f;
    for (int o = 32; o > 0; o >>= 1) e += __shfl_down(e, o);
    if (t == 0) out[0] = m + logf(e);
}

extern "C" void kernel_launch(void* const* d_in, const int* in_sizes, int n_in,
                              void* d_out, int out_size, void* d_ws, size_t ws_size,
                              hipStream_t stream) {
    const float* unary = (const float*)d_in[0];  // (48,60)
    const float* rule  = (const float*)d_in[1];  // (30,90,90)
    const float* root  = (const float*)d_in[2];  // (30,)
    float* out = (float*)d_out;

    float*          ws     = (float*)d_ws;
    unsigned short* eruleB = (unsigned short*)ws;           // 276480 ushorts
    unsigned short* svec   = eruleB + 30 * 36 * 256;        // 221184 ushorts
    float*          scal   = (float*)(svec + NN * NN * 96); // 2304 floats
    unsigned*       mkey   = (unsigned*)(scal + NN * NN);   // 2304

    k_prep<<<1128, 64, 0, stream>>>(rule, unary, eruleB, svec, scal, mkey);
    for (int l = 1; l < NN; ++l) {
        k_level<<<dim3(NN - l, 30), 384, 0, stream>>>(l, eruleB, svec, scal, mkey);
    }
    k_final<<<1, 64, 0, stream>>>(root, svec, scal, out);
}